// Round 5
// baseline (34.075 us; speedup 1.0000x reference)
//
#include <hip/hip_runtime.h>
#include <hip/hip_fp16.h>

#define SIGMA_C 1e-4f
#define EPS_C   1e-12f
#define WPB     4          // waves per block
#define TILE_T  8          // tiles (of 64 pairs) per wave

struct V3 { float x, y, z; };

__device__ __forceinline__ V3 v3sub(V3 a, V3 b) { return {a.x - b.x, a.y - b.y, a.z - b.z}; }
__device__ __forceinline__ float v3dot(V3 a, V3 b) { return a.x * b.x + a.y * b.y + a.z * b.z; }
__device__ __forceinline__ V3 v3cross(V3 a, V3 b) {
    return {a.y * b.z - a.z * b.y,
            a.z * b.x - a.x * b.z,
            a.x * b.y - a.y * b.x};
}
__device__ __forceinline__ int imax0(int x) { return x > 0 ? x : 0; }

__device__ __forceinline__ void tri_frame(const V3 v[3], V3& c, V3& n, float& r) {
    const float third = 1.0f / 3.0f;
    c.x = (v[0].x + v[1].x + v[2].x) * third;
    c.y = (v[0].y + v[1].y + v[2].y) * third;
    c.z = (v[0].z + v[1].z + v[2].z) * third;
    V3 e1 = v3sub(v[1], v[0]);
    V3 e2 = v3sub(v[2], v[0]);
    n = v3cross(e1, e2);
    float nn = sqrtf(v3dot(n, n));
    float inv = 1.0f / fmaxf(nn, EPS_C);
    n.x *= inv; n.y *= inv; n.z *= inv;
    V3 d0 = v3sub(v[0], c), d1 = v3sub(v[1], c), d2 = v3sub(v[2], c);
    float m = fmaxf(fmaxf(v3dot(d0, d0), v3dot(d1, d1)), v3dot(d2, d2));
    r = sqrtf(m);
}

__device__ __forceinline__ float cone_psi2(const V3 p[3], V3 c, V3 n, float r) {
    float inv_r = 1.0f / fmaxf(r, EPS_C);
    float s = 0.0f;
#pragma unroll
    for (int i = 0; i < 3; ++i) {
        V3 u = v3sub(p[i], c);
        float h = v3dot(u, n);
        V3 w = {u.x - h * n.x, u.y - h * n.y, u.z - h * n.z};
        float rho = sqrtf(v3dot(w, w));
        float radial = fmaxf(1.0f - rho * inv_r, 0.0f);
        float axial = fmaxf(SIGMA_C - h, 0.0f);   // PENALIZE_OUTSIDE = True
        float psi = radial * axial;
        s += psi * psi;
    }
    return s;
}

// fp16 record: 16 halves = 32 B. h[0..2]=v0 h[3..5]=v1 h[6..8]=v2 h[9..11]=c h[12..14]=n h[15]=r
union RecU { float4 f[2]; __half h[16]; };

__device__ __forceinline__ void unpack_rec_h(float4 a, float4 b,
                                             V3 p[3], V3& c, V3& n, float& r) {
    RecU u; u.f[0] = a; u.f[1] = b;
    p[0] = {__half2float(u.h[0]),  __half2float(u.h[1]),  __half2float(u.h[2])};
    p[1] = {__half2float(u.h[3]),  __half2float(u.h[4]),  __half2float(u.h[5])};
    p[2] = {__half2float(u.h[6]),  __half2float(u.h[7]),  __half2float(u.h[8])};
    c = {__half2float(u.h[9]),  __half2float(u.h[10]), __half2float(u.h[11])};
    n = {__half2float(u.h[12]), __half2float(u.h[13]), __half2float(u.h[14])};
    r = __half2float(u.h[15]);
}

__device__ __forceinline__ float compute_pair(const float4 G0, const float4 G1,
                                              const float4 G2, const float4 G3, float w) {
    V3 rp[3], rc, rn; float rr;
    unpack_rec_h(G0, G1, rp, rc, rn, rr);
    V3 ip[3], ic, inn; float ir;
    unpack_rec_h(G2, G3, ip, ic, inn, ir);
    return w * (cone_psi2(ip, rc, rn, rr) + cone_psi2(rp, ic, inn, ir));
}

__device__ __forceinline__ void gload_lds16(const void* g, void* l) {
    __builtin_amdgcn_global_load_lds((const __attribute__((address_space(1))) void*)g,
                                     (__attribute__((address_space(3))) void*)l,
                                     16, 0, 0);
}

// ---------------- phase 1: per-(batch,face) 32-B fp16 record, 2 faces/thread ----------------
__global__ void precompute_tri_h(const float* __restrict__ verts,  // [B,V,3]
                                 const int*   __restrict__ faces,  // [F,3]
                                 float4* __restrict__ table,       // [B*F*2]
                                 float* __restrict__ out,          // [B]
                                 int V, int F, int B) {
    if (blockIdx.x == 0 && threadIdx.x < (unsigned)B)
        out[threadIdx.x] = 0.0f;

    const int b = blockIdx.x % B;      // batch -> XCD co-location with pair kernel
    const int chunk = blockIdx.x / B;
    const int f0 = (chunk * blockDim.x + threadIdx.x) * 2;
    if (f0 >= F) return;
    const int nf = (f0 + 1 < F) ? 2 : 1;

    const float* vb = verts + (size_t)b * (size_t)V * 3u;

    // branchless straight-line: all index loads, then all vertex loads
    int ia[6];
#pragma unroll
    for (int j = 0; j < 3; ++j) ia[j] = faces[3 * f0 + j];
#pragma unroll
    for (int j = 0; j < 3; ++j) ia[3 + j] = faces[3 * (f0 + nf - 1) + j];

    V3 pv[6];
#pragma unroll
    for (int j = 0; j < 6; ++j) {
        int vi = ia[j];
        pv[j] = {vb[3 * vi + 0], vb[3 * vi + 1], vb[3 * vi + 2]};
    }

#pragma unroll
    for (int k = 0; k < 2; ++k) {
        if (k >= nf) break;
        V3 v[3] = {pv[3 * k], pv[3 * k + 1], pv[3 * k + 2]};
        V3 c, n; float r;
        tri_frame(v, c, n, r);
        RecU u;
        u.h[0]  = __float2half(v[0].x); u.h[1]  = __float2half(v[0].y); u.h[2]  = __float2half(v[0].z);
        u.h[3]  = __float2half(v[1].x); u.h[4]  = __float2half(v[1].y); u.h[5]  = __float2half(v[1].z);
        u.h[6]  = __float2half(v[2].x); u.h[7]  = __float2half(v[2].y); u.h[8]  = __float2half(v[2].z);
        u.h[9]  = __float2half(c.x);    u.h[10] = __float2half(c.y);    u.h[11] = __float2half(c.z);
        u.h[12] = __float2half(n.x);    u.h[13] = __float2half(n.y);    u.h[14] = __float2half(n.z);
        u.h[15] = __float2half(r);
        float4* rec = table + ((size_t)b * F + (f0 + k)) * 2;
        rec[0] = u.f[0];
        rec[1] = u.f[1];
    }
}

// ---------------- phase 2: global_load_lds gather pipeline ----------------
__global__ void __launch_bounds__(WPB * 64)
pair_kernel_lds(const float4* __restrict__ table,  // [B*F*2]
                const int2*  __restrict__ coll,    // [B*C]
                float* __restrict__ out,           // [B]
                int F, int C, int B) {
    __shared__ float4 lds[WPB * 2 * 256];          // per wave: 2 bufs x 256 float4 (4 KB)
    __shared__ float red[WPB];

    const int wid  = threadIdx.x >> 6;
    const int lane = threadIdx.x & 63;
    const int b = blockIdx.x % B;                  // batch -> XCD pinning
    const int chunk = blockIdx.x / B;
    const int wib = chunk * WPB + wid;             // wave index within batch

    const int2* cb = coll + (size_t)b * C;
    const char* tb = (const char*)(table + (size_t)b * ((size_t)F * 2));
    float4* wbuf = lds + wid * 512;

    // preload all tile indices (coalesced 8B/lane); compiler auto-waits on use
    int2 q[TILE_T];
    const int pair0 = wib * (TILE_T * 64) + lane;
#pragma unroll
    for (int t = 0; t < TILE_T; ++t)
        q[t] = cb[pair0 + t * 64];

    // issue tile 0 gathers (4 x 64-wide 16-B gather)
    {
        const char* gR = tb + (size_t)imax0(q[0].x) * 32;
        const char* gI = tb + (size_t)imax0(q[0].y) * 32;
        gload_lds16(gR,      wbuf);
        gload_lds16(gR + 16, wbuf + 64);
        gload_lds16(gI,      wbuf + 128);
        gload_lds16(gI + 16, wbuf + 192);
    }

    float acc = 0.0f;
#pragma unroll
    for (int t = 0; t < TILE_T; ++t) {
        if (t + 1 < TILE_T) {
            const char* gR = tb + (size_t)imax0(q[t + 1].x) * 32;
            const char* gI = tb + (size_t)imax0(q[t + 1].y) * 32;
            float4* dst = wbuf + ((t + 1) & 1) * 256;
            gload_lds16(gR,      dst);
            gload_lds16(gR + 16, dst + 64);
            gload_lds16(gI,      dst + 128);
            gload_lds16(gI + 16, dst + 192);
            __builtin_amdgcn_sched_barrier(0);
            asm volatile("s_waitcnt vmcnt(4)" ::: "memory");   // tile t done; t+1 in flight
            __builtin_amdgcn_sched_barrier(0);
        } else {
            __builtin_amdgcn_sched_barrier(0);
            asm volatile("s_waitcnt vmcnt(0)" ::: "memory");
            __builtin_amdgcn_sched_barrier(0);
        }
        const float4* src = wbuf + (t & 1) * 256;
        float4 a0 = src[lane];
        float4 a1 = src[lane + 64];
        float4 a2 = src[lane + 128];
        float4 a3 = src[lane + 192];
        float w = ((q[t].x | q[t].y) >= 0) ? 1.0f : 0.0f;
        acc += compute_pair(a0, a1, a2, a3, w);
    }

    // wave shuffle reduction
#pragma unroll
    for (int off = 32; off > 0; off >>= 1)
        acc += __shfl_down(acc, off, 64);

    if (lane == 0) red[wid] = acc;
    __syncthreads();
    if (threadIdx.x == 0) {
        float s = 0.0f;
#pragma unroll
        for (int i = 0; i < WPB; ++i) s += red[i];
        atomicAdd(&out[b], s);
    }
}

// ---------------- fallback A: register-pipelined (round-4) ----------------
#define GPT 4
__device__ __forceinline__ void gather_group(const float4* __restrict__ tb, int4 q,
                                             float4 G[8], float w[2]) {
    w[0] = ((q.x | q.y) >= 0) ? 1.0f : 0.0f;
    w[1] = ((q.z | q.w) >= 0) ? 1.0f : 0.0f;
    const float4* R0 = tb + (size_t)imax0(q.x) * 2;
    const float4* I0 = tb + (size_t)imax0(q.y) * 2;
    const float4* R1 = tb + (size_t)imax0(q.z) * 2;
    const float4* I1 = tb + (size_t)imax0(q.w) * 2;
    G[0] = R0[0]; G[1] = R0[1];
    G[2] = I0[0]; G[3] = I0[1];
    G[4] = R1[0]; G[5] = R1[1];
    G[6] = I1[0]; G[7] = I1[1];
}
__device__ __forceinline__ float compute_group(const float4 G[8], const float w[2]) {
    return compute_pair(G[0], G[1], G[2], G[3], w[0]) +
           compute_pair(G[4], G[5], G[6], G[7], w[1]);
}
__global__ void __launch_bounds__(256)
pair_kernel_h(const float4* __restrict__ table, const int4* __restrict__ coll4,
              float* __restrict__ out, int F, int C4, int B) {
    const int b = blockIdx.x % B;
    const int chunk = blockIdx.x / B;
    const int4* cb = coll4 + (size_t)b * C4;
    const float4* tb = table + (size_t)b * ((size_t)F * 2);
    const int base = chunk * (256 * GPT) + threadIdx.x;

    float acc = 0.0f;
    float4 GA[8], GB[8];
    float wA[2], wB[2];
    int4 q_even, q_odd;
    {
        int g0 = base, g1 = base + 256;
        q_even = (g0 < C4) ? cb[g0] : make_int4(-1, -1, -1, -1);
        q_odd  = (g1 < C4) ? cb[g1] : make_int4(-1, -1, -1, -1);
        gather_group(tb, q_even, GA, wA);
    }
#pragma unroll
    for (int i = 0; i < GPT; ++i) {
        if ((i & 1) == 0) {
            if (i + 2 < GPT) {
                int g = base + (i + 2) * 256;
                q_even = (g < C4) ? cb[g] : make_int4(-1, -1, -1, -1);
            }
            if (i + 1 < GPT) gather_group(tb, q_odd, GB, wB);
            acc += compute_group(GA, wA);
        } else {
            if (i + 2 < GPT) {
                int g = base + (i + 2) * 256;
                q_odd = (g < C4) ? cb[g] : make_int4(-1, -1, -1, -1);
            }
            if (i + 1 < GPT) gather_group(tb, q_even, GA, wA);
            acc += compute_group(GB, wB);
        }
    }
#pragma unroll
    for (int off = 32; off > 0; off >>= 1)
        acc += __shfl_down(acc, off, 64);
    __shared__ float red[4];
    int lane = threadIdx.x & 63, wid = threadIdx.x >> 6;
    if (lane == 0) red[wid] = acc;
    __syncthreads();
    if (threadIdx.x == 0) {
        float s = 0.0f;
        for (int i = 0; i < 4; ++i) s += red[i];
        atomicAdd(&out[b], s);
    }
}

// ---------------- fallback B: direct gather ----------------
__global__ void interp_zero(float* out, int n) {
    int i = blockIdx.x * blockDim.x + threadIdx.x;
    if (i < n) out[i] = 0.0f;
}
__global__ void pair_kernel_gather(const float* __restrict__ verts,
                                   const int*   __restrict__ faces,
                                   const int2*  __restrict__ coll,
                                   float* __restrict__ out, int V, int C) {
    const int b = blockIdx.y;
    const float* vb = verts + (size_t)b * (size_t)V * 3u;
    const int2* cb = coll + (size_t)b * (size_t)C;
    float acc = 0.0f;
    const int stride = gridDim.x * blockDim.x;
    for (int c = blockIdx.x * blockDim.x + threadIdx.x; c < C; c += stride) {
        int2 idx = cb[c];
        if ((idx.x | idx.y) >= 0) {
            const int* fr = faces + 3 * idx.x;
            const int* fi = faces + 3 * idx.y;
            V3 tr[3], ti[3];
#pragma unroll
            for (int j = 0; j < 3; ++j) {
                int vr = fr[j];
                tr[j] = {vb[3 * vr + 0], vb[3 * vr + 1], vb[3 * vr + 2]};
                int vi = fi[j];
                ti[j] = {vb[3 * vi + 0], vb[3 * vi + 1], vb[3 * vi + 2]};
            }
            V3 rc, rn; float rr;
            tri_frame(tr, rc, rn, rr);
            V3 ic, in_; float ir;
            tri_frame(ti, ic, in_, ir);
            acc += cone_psi2(ti, rc, rn, rr);
            acc += cone_psi2(tr, ic, in_, ir);
        }
    }
#pragma unroll
    for (int off = 32; off > 0; off >>= 1)
        acc += __shfl_down(acc, off, 64);
    __shared__ float red[16];
    int lane = threadIdx.x & 63, wid = threadIdx.x >> 6;
    if (lane == 0) red[wid] = acc;
    __syncthreads();
    if (threadIdx.x == 0) {
        float s = 0.0f;
        int nw = blockDim.x >> 6;
        for (int i = 0; i < nw; ++i) s += red[i];
        atomicAdd(&out[b], s);
    }
}

extern "C" void kernel_launch(void* const* d_in, const int* in_sizes, int n_in,
                              void* d_out, int out_size, void* d_ws, size_t ws_size,
                              hipStream_t stream) {
    const float* verts = (const float*)d_in[0];
    const int*   faces = (const int*)d_in[1];
    float* out = (float*)d_out;

    const int B = out_size;                       // 8
    const int V = in_sizes[0] / (3 * B);          // 10475
    const int F = in_sizes[1] / 3;                // 20908
    const int C = in_sizes[2] / (2 * B);          // 262144

    const size_t table_bytes = (size_t)B * (size_t)F * 32u;
    const int pairs_per_block = 64 * TILE_T * WPB;          // 2048

    if (ws_size >= table_bytes) {
        float4* table = (float4*)d_ws;

        const int pchunks = (F + 511) / 512;                // 2 faces/thread
        precompute_tri_h<<<dim3(pchunks * B), dim3(256), 0, stream>>>(
            verts, faces, table, out, V, F, B);

        if (C % pairs_per_block == 0) {
            const int BPB = C / pairs_per_block;            // 128
            pair_kernel_lds<<<dim3(BPB * B), dim3(WPB * 64), 0, stream>>>(
                table, (const int2*)d_in[2], out, F, C, B);
        } else if ((C % 2) == 0) {
            const int C4 = C / 2;
            const int chunks = (C4 + 256 * GPT - 1) / (256 * GPT);
            pair_kernel_h<<<dim3(chunks * B), dim3(256), 0, stream>>>(
                table, (const int4*)d_in[2], out, F, C4, B);
        } else {
            interp_zero<<<1, 64, 0, stream>>>(out, B);
            pair_kernel_gather<<<dim3(256, B), dim3(256), 0, stream>>>(
                verts, faces, (const int2*)d_in[2], out, V, C);
        }
    } else {
        interp_zero<<<1, 64, 0, stream>>>(out, B);
        pair_kernel_gather<<<dim3(256, B), dim3(256), 0, stream>>>(
            verts, faces, (const int2*)d_in[2], out, V, C);
    }
}